// Round 19
// baseline (218.767 us; speedup 1.0000x reference)
//
#include <hip/hip_runtime.h>
#include <hip/hip_bf16.h>

// Problem constants
#define NBS   128
#define NF    182      // 20 text + 150 ocr/obj + 12 decode
#define NP    192      // padded N for MFMA tiling
#define DMODEL 768
#define NH    12
#define HDIM  64
#define SEQT  20
#define ROCR  150

typedef __attribute__((ext_vector_type(4))) float  f32x4;
typedef __attribute__((ext_vector_type(8))) short  s16x8;
typedef __attribute__((ext_vector_type(4))) unsigned int u32x4;
using bf16 = __hip_bfloat16;

#define SB()    __builtin_amdgcn_sched_barrier(0)
#define BAR()   __builtin_amdgcn_s_barrier()

// global->LDS direct copy, 16B per lane. LDS dest linear in lane (base+lane*16).
__device__ __forceinline__ void gload_lds16(const void* g, void* l) {
    auto gp = (const __attribute__((address_space(1))) unsigned int*)((unsigned long long)g);
    auto lp = (__attribute__((address_space(3))) unsigned int*)(unsigned int)((unsigned long long)l);
    __builtin_amdgcn_global_load_lds(gp, lp, 16, 0, 0);
}

// ---------------------------------------------------------------------------
// Kernel 0: PREP (convert + pack_adj merged).
// Blocks [0, 9600): fp32->bf16: hs -> hsb; Wq|Wk|Wv -> Wb2 per-head layout
//   (Wb2 row R = h*192 + which*64 + r0 holds W_which[h*64+r0][:]).
// Blocks [9600, 28800): pack spatial adjacency -> bitmask (b,12,150,3).
// ---------------------------------------------------------------------------
#define CVT_BLOCKS 9600
__global__ __launch_bounds__(256) void prep(
    const float* __restrict__ hs,
    const float* __restrict__ Wq, const float* __restrict__ Wk, const float* __restrict__ Wv,
    const float* __restrict__ adj,
    bf16* __restrict__ hsb, bf16* __restrict__ Wb2,
    unsigned long long* __restrict__ bits)
{
    __shared__ float tile[ROCR * NH];       // used by pack branch only
    if (blockIdx.x < CVT_BLOCKS) {
        const size_t HT = (size_t)NBS * NF * DMODEL / 8;        // 2,236,416
        const size_t WT = 3ull * DMODEL * DMODEL / 8;           // 221,184
        size_t i = (size_t)blockIdx.x * 256 + threadIdx.x;
        if (i >= HT + WT) return;
        const float* src; bf16* dst;
        if (i < HT) {
            size_t e = i * 8; src = hs + e; dst = hsb + e;
        } else {
            size_t e = (i - HT) * 8;
            int R = (int)(e / DMODEL), c = (int)(e % DMODEL);
            int h = R / 192, t2 = (R % 192) / 64, r0 = R % 64;
            src = (t2 == 0 ? Wq : t2 == 1 ? Wk : Wv) + (size_t)(h * 64 + r0) * DMODEL + c;
            dst = Wb2 + e;
        }
        float4 a = *reinterpret_cast<const float4*>(src);
        float4 b = *reinterpret_cast<const float4*>(src + 4);
        union { s16x8 v; bf16 h8[8]; } u;
        u.h8[0] = __float2bfloat16(a.x); u.h8[1] = __float2bfloat16(a.y);
        u.h8[2] = __float2bfloat16(a.z); u.h8[3] = __float2bfloat16(a.w);
        u.h8[4] = __float2bfloat16(b.x); u.h8[5] = __float2bfloat16(b.y);
        u.h8[6] = __float2bfloat16(b.z); u.h8[7] = __float2bfloat16(b.w);
        *reinterpret_cast<s16x8*>(dst) = u.v;
    } else {
        const int pb = blockIdx.x - CVT_BLOCKS;
        const int b = pb / ROCR, r = pb - b * ROCR;
        const int tid = threadIdx.x, lane = tid & 63, w = tid >> 6;
        const float* src = adj + ((size_t)b * ROCR + r) * (ROCR * NH);
        for (int i = tid; i < ROCR * NH; i += 256) tile[i] = src[i];
        __syncthreads();
        for (int c = w; c < NH * 3; c += 4) {
            int hh = c / 3, wd = c - hh * 3;
            int k = wd * 64 + lane;
            int j = k - SEQT;
            bool v = false;
            if (j >= 0 && j < ROCR) v = (tile[j * NH + hh] > 0.5f);
            unsigned long long m = __ballot(v);
            if (lane == 0) bits[(((size_t)b * NH + hh) * ROCR + r) * 3 + wd] = m;
        }
    }
}

// ---------------------------------------------------------------------------
// Kernel 2: FUSED per-(b,h) QKV-projection + attention, 12-WAVE RE-TILE.
// 768 threads, wave grid 4x3: each wave owns a 48x64 GEMM tile -> acc shrinks
// 144 -> 48 regs/wave; total regs <= ~128 -> 3 waves/SIMD resident (vs 2 at
// the old 96x96 tiling — R15-R17 proved occupancy was register-bound).
// Epilogue columns are uniform per wave (wc=0 -> Q, 1 -> K, 2 -> V).
// Staging: exactly 1 A-load + 1 W-load per thread per tile (vmcnt 4/2/0).
// Attention: 1 band per wave (waves 0..10), verified in-register-P body.
// LDS map:
//   [0..24576)      staging buf0 -> K[192][64] swz after GEMM
//   [24576..49152)  staging buf1 -> Vt[64][192] swz after GEMM
//   [49152..73728)  staging buf2 -> Q[192][64] swz (x0.125) after GEMM
// ---------------------------------------------------------------------------
#define KO2   0
#define VTO2  24576
#define QO3   49152

__global__ __launch_bounds__(768, 1) void fused_qkv_attn(
    const bf16* __restrict__ hsb, const bf16* __restrict__ Wb2,
    const float* __restrict__ bq, const float* __restrict__ bk, const float* __restrict__ bv,
    const float* __restrict__ amask,
    const unsigned long long* __restrict__ bits,
    float* __restrict__ out)
{
    __shared__ char L[73728];
    const int tid  = threadIdx.x;
    const int lane = tid & 63;
    const int wid  = tid >> 6;                  // 0..11
    const int wr = wid / 3, wc = wid - wr * 3;  // 4x3 wave grid: 48-row x 64-col
    const int lm = lane & 15, lg = lane >> 4;

    // m204 XCD chunking (1536 = 8*192): 12 head-blocks of one b on one XCD.
    const int flat = blockIdx.x;
    const int wgid = (flat & 7) * 192 + (flat >> 3);
    const int b = wgid / NH, h = wgid - b * NH;

    float* obase = out + (size_t)b * NF * DMODEL + h * HDIM;

    // ---- aw: amask ballot words, per-wave registers (no LDS, no sync) ----
    unsigned long long aw0, aw1, aw2;
    {
        int k0 = lane, k1 = 64 + lane, k2 = 128 + lane;
        aw0 = __ballot(amask[b * NF + k0] == 0.0f);
        aw1 = __ballot(amask[b * NF + k1] == 0.0f);
        aw2 = __ballot((k2 < NF) && (amask[b * NF + k2] == 0.0f));
    }
    // decode output rows are exactly zero (12*64 = 768 = blockDim)
    obase[(size_t)(170 + (tid >> 6)) * DMODEL + (tid & 63)] = 0.f;

    // ---- Phase G: GEMM (BK=32, 3-deep staging pipeline, vmcnt(4)) ----
    const char* gA = (const char*)(hsb + (size_t)b * NF * DMODEL);   // 192 rows (pad rows in slack)
    const char* gW = (const char*)(Wb2 + (size_t)h * 192 * DMODEL);

    f32x4 acc[3][4];
    #pragma unroll
    for (int i = 0; i < 3; ++i)
        #pragma unroll
        for (int j = 0; j < 4; ++j) acc[i][j] = (f32x4){0.f, 0.f, 0.f, 0.f};

    const int srow = tid >> 2, sch = tid & 3;   // 192 rows x 4 chunks = 768 thr

    auto ST = [&](int kt, int bsel) {
        char* dA = L + bsel * 24576;
        int lc = sch ^ ((srow >> 1) & 3);
        size_t go = (size_t)srow * 1536 + (size_t)kt * 64 + lc * 16;
        int o = srow * 64 + sch * 16;
        gload_lds16(gA + go, dA + o);
        gload_lds16(gW + go, dA + 12288 + o);
    };
    auto CP = [&](int bsel) {
        const char* Ab = L + bsel * 24576;
        const char* Wp = Ab + 12288;
        s16x8 af[3], bf4[4];
        #pragma unroll
        for (int mi = 0; mi < 3; ++mi) {
            int r = 48 * wr + 16 * mi + lm;
            af[mi] = *reinterpret_cast<const s16x8*>(Ab + r * 64 + ((lg ^ ((r >> 1) & 3)) << 4));
        }
        #pragma unroll
        for (int ni = 0; ni < 4; ++ni) {
            int r = 64 * wc + 16 * ni + lm;
            bf4[ni] = *reinterpret_cast<const s16x8*>(Wp + r * 64 + ((lg ^ ((r >> 1) & 3)) << 4));
        }
        __builtin_amdgcn_s_setprio(1);
        #pragma unroll
        for (int mi = 0; mi < 3; ++mi)
            #pragma unroll
            for (int ni = 0; ni < 4; ++ni)
                acc[mi][ni] = __builtin_amdgcn_mfma_f32_16x16x32_bf16(af[mi], bf4[ni], acc[mi][ni], 0, 0, 0);
        __builtin_amdgcn_s_setprio(0);
    };

    ST(0, 0);
    ST(1, 1);
    ST(2, 2);
    for (int t = 0; t < 24; ++t) {
        if (t <= 21)      { asm volatile("s_waitcnt vmcnt(4)" ::: "memory"); }
        else if (t == 22) { asm volatile("s_waitcnt vmcnt(2)" ::: "memory"); }
        else              { asm volatile("s_waitcnt vmcnt(0)" ::: "memory"); }
        SB(); BAR(); SB();
        CP(t % 3);
        SB(); BAR();
        if (t + 3 < 24) ST(t + 3, t % 3);
    }
    BAR();   // all CP reads done before epilogue overwrites staging region

    // ---- epilogue (SINGLE PASS): per wave, cols are uniformly Q|K|V ----
    {
        const float* bp = (wc == 0) ? bq : (wc == 1) ? bk : bv;
        float bias4[4];
        #pragma unroll
        for (int ni = 0; ni < 4; ++ni) bias4[ni] = bp[h * 64 + 16 * ni + lm];

        #pragma unroll
        for (int mi = 0; mi < 3; ++mi) {
            int row0 = 48 * wr + 16 * mi + 4 * lg;
            #pragma unroll
            for (int ni = 0; ni < 4; ++ni) {
                int c = 16 * ni + lm;           // 0..63 within this operand
                if (wc == 0) {
                    // Q, pre-scaled by 1/8 (exact pow2)
                    #pragma unroll
                    for (int j = 0; j < 4; ++j) {
                        int row = row0 + j;
                        if (row < 176) {
                            bf16 hv = __float2bfloat16((acc[mi][ni][j] + bias4[ni]) * 0.125f);
                            *reinterpret_cast<unsigned short*>(L + QO3 + row * 128 + ((2 * c) ^ ((row & 7) << 4))) =
                                *reinterpret_cast<unsigned short*>(&hv);
                        }
                    }
                } else if (wc == 1) {
                    #pragma unroll
                    for (int j = 0; j < 4; ++j) {
                        int row = row0 + j;
                        bf16 hv = __float2bfloat16(acc[mi][ni][j] + bias4[ni]);
                        *reinterpret_cast<unsigned short*>(L + KO2 + row * 128 + ((2 * c) ^ ((row & 7) << 4))) =
                            *reinterpret_cast<unsigned short*>(&hv);
                    }
                } else {
                    int d = c;
                    if (row0 + 3 < NF) {
                        union { unsigned long long u8; bf16 h4[4]; } pk;
                        pk.h4[0] = __float2bfloat16(acc[mi][ni][0] + bias4[ni]);
                        pk.h4[1] = __float2bfloat16(acc[mi][ni][1] + bias4[ni]);
                        pk.h4[2] = __float2bfloat16(acc[mi][ni][2] + bias4[ni]);
                        pk.h4[3] = __float2bfloat16(acc[mi][ni][3] + bias4[ni]);
                        *reinterpret_cast<unsigned long long*>(L + VTO2 + d * 384 + ((2 * row0) ^ ((d & 7) << 4))) = pk.u8;
                    } else {
                        #pragma unroll
                        for (int j = 0; j < 4; ++j) {
                            int row = row0 + j;
                            if (row < NF) {
                                bf16 hv = __float2bfloat16(acc[mi][ni][j] + bias4[ni]);
                                *reinterpret_cast<unsigned short*>(L + VTO2 + d * 384 + ((2 * row) ^ ((d & 7) << 4))) =
                                    *reinterpret_cast<unsigned short*>(&hv);
                            }
                        }
                    }
                }
            }
        }
    }
    // zero Vt pad keys 182..191 (only writer of these addresses -> race-free)
    for (int i = tid; i < 64 * 10; i += 768) {
        int d = i / 10, k2 = NF + (i - d * 10);
        *reinterpret_cast<unsigned short*>(L + VTO2 + d * 384 + ((2 * k2) ^ ((d & 7) << 4))) = 0;
    }
    __syncthreads();

    // ---- Q-preload from LDS: one band per wave ----
    const int band = (wid < 11) ? wid : 0;
    s16x8 qf0, qf1;
    {
        int qrow = band * 16 + lm;
        const char* qb = L + QO3 + qrow * 128;
        int sq = (qrow & 7) << 4;
        qf0 = *reinterpret_cast<const s16x8*>(qb + ((lg * 16) ^ sq));
        qf1 = *reinterpret_cast<const s16x8*>(qb + ((64 + lg * 16) ^ sq));
    }

    // ---- Phase A: attention, P fully in-register (verified body) ----
    if (wid < 11) {
        const unsigned long long* bbase = bits + ((size_t)b * NH + h) * ROCR * 3;
        const unsigned long long DEC = 0xFFFull << 42;      // keys 170..181
        const int q0 = band * 16;

        const int qrow = q0 + lm;
        unsigned long long mw0, mw1, mw2;
        if (qrow < SEQT) {
            mw0 = 0; mw1 = 0; mw2 = DEC & aw2;
        } else {
            const unsigned long long* bp = bbase + (size_t)(qrow - SEQT) * 3;
            mw0 = bp[0] & aw0;
            mw1 = bp[1] & aw1;
            mw2 = (bp[2] | DEC) & aw2;
        }

        // swapped QK^T: sacc[t][j] = S[key=16t+4lg+j][qrow] (pre-scaled)
        f32x4 sacc[12];
        #pragma unroll
        for (int t = 0; t < 12; ++t) sacc[t] = (f32x4){0.f, 0.f, 0.f, 0.f};
        #pragma unroll
        for (int t = 0; t < 12; ++t) {
            int key = t * 16 + lm;
            const char* kb = L + KO2 + key * 128;
            int sw = (key & 7) << 4;
            s16x8 kf0 = *reinterpret_cast<const s16x8*>(kb + ((lg * 16) ^ sw));
            s16x8 kf1 = *reinterpret_cast<const s16x8*>(kb + ((64 + lg * 16) ^ sw));
            sacc[t] = __builtin_amdgcn_mfma_f32_16x16x32_bf16(kf0, qf0, sacc[t], 0, 0, 0);
            sacc[t] = __builtin_amdgcn_mfma_f32_16x16x32_bf16(kf1, qf1, sacc[t], 0, 0, 0);
        }

        // mask + per-lane softmax (this lane owns one q-row)
        float mx = -3.0e38f;
        #pragma unroll
        for (int t = 0; t < 12; ++t) {
            unsigned long long w = (t < 4) ? mw0 : (t < 8) ? mw1 : mw2;
            #pragma unroll
            for (int j = 0; j < 4; ++j) {
                int sh = ((t & 3) << 4) + 4 * lg + j;
                float s = sacc[t][j];
                s = ((w >> sh) & 1ull) ? s : -3.0e38f;
                sacc[t][j] = s;
                mx = fmaxf(mx, s);
            }
        }
        mx = fmaxf(mx, __shfl_xor(mx, 16));
        mx = fmaxf(mx, __shfl_xor(mx, 32));
        float sum = 0.f;
        #pragma unroll
        for (int t = 0; t < 12; ++t)
            #pragma unroll
            for (int j = 0; j < 4; ++j) {
                float e = (sacc[t][j] > -1.0e37f) ? __expf(sacc[t][j] - mx) : 0.f;
                sacc[t][j] = e;
                sum += e;
            }
        sum += __shfl_xor(sum, 16);
        sum += __shfl_xor(sum, 32);
        float scl = (mx > -1.0e37f) ? 1.0f / sum : 0.f;

        // pack P rows to bf16 dword pairs per tile
        unsigned int p0[12], p1[12];
        #pragma unroll
        for (int t = 0; t < 12; ++t) {
            bf16 b0 = __float2bfloat16(sacc[t][0] * scl);
            bf16 b1 = __float2bfloat16(sacc[t][1] * scl);
            bf16 b2 = __float2bfloat16(sacc[t][2] * scl);
            bf16 b3 = __float2bfloat16(sacc[t][3] * scl);
            p0[t] = (unsigned int)*reinterpret_cast<unsigned short*>(&b0)
                  | ((unsigned int)*reinterpret_cast<unsigned short*>(&b1) << 16);
            p1[t] = (unsigned int)*reinterpret_cast<unsigned short*>(&b2)
                  | ((unsigned int)*reinterpret_cast<unsigned short*>(&b3) << 16);
        }

        // PV: build A-frags by lane exchange; dest (lg,ks) = keys 32ks+8lg+0..7
        f32x4 oacc[4];
        #pragma unroll
        for (int t = 0; t < 4; ++t) oacc[t] = (f32x4){0.f, 0.f, 0.f, 0.f};
        const bool hi = (lg & 1);
        #pragma unroll
        for (int ks = 0; ks < 6; ++ks) {
            unsigned int A0 = p0[2 * ks],     A1 = p1[2 * ks];
            unsigned int B0 = p0[2 * ks + 1], B1 = p1[2 * ks + 1];
            unsigned int u0 = __shfl_xor(A0, 16), u1 = __shfl_xor(A1, 16);
            unsigned int v0 = __shfl_xor(B0, 16), v1 = __shfl_xor(B1, 16);
            unsigned int hA0 = hi ? u0 : A0, hA1 = hi ? u1 : A1;
            unsigned int hA2 = hi ? A0 : u0, hA3 = hi ? A1 : u1;
            unsigned int hB0 = hi ? v0 : B0, hB1 = hi ? v1 : B1;
            unsigned int hB2 = hi ? B0 : v0, hB3 = hi ? B1 : v1;
            unsigned int xA0 = __shfl_xor(hA0, 32), xA1 = __shfl_xor(hA1, 32);
            unsigned int xA2 = __shfl_xor(hA2, 32), xA3 = __shfl_xor(hA3, 32);
            unsigned int xB0 = __shfl_xor(hB0, 32), xB1 = __shfl_xor(hB1, 32);
            unsigned int xB2 = __shfl_xor(hB2, 32), xB3 = __shfl_xor(hB3, 32);
            u32x4 f;
            if (lg == 0)      f = (u32x4){hA0, hA1, hA2, hA3};
            else if (lg == 1) f = (u32x4){xA0, xA1, xA2, xA3};
            else if (lg == 2) f = (u32x4){xB0, xB1, xB2, xB3};
            else              f = (u32x4){hB0, hB1, hB2, hB3};
            s16x8 pa;
            __builtin_memcpy(&pa, &f, 16);
            #pragma unroll
            for (int t2 = 0; t2 < 4; ++t2) {
                int d = t2 * 16 + lm;
                s16x8 vf = *reinterpret_cast<const s16x8*>(L + VTO2 + d * 384 + ((ks * 64 + lg * 16) ^ ((d & 7) << 4)));
                oacc[t2] = __builtin_amdgcn_mfma_f32_16x16x32_bf16(pa, vf, oacc[t2], 0, 0, 0);
            }
        }
        #pragma unroll
        for (int j = 0; j < 4; ++j) {
            int row = q0 + lg * 4 + j;
            if (row < 170) {
                #pragma unroll
                for (int t2 = 0; t2 < 4; ++t2)
                    obase[(size_t)row * DMODEL + t2 * 16 + lm] = oacc[t2][j];
            }
        }
    }
}

// ---------------------------------------------------------------------------
extern "C" void kernel_launch(void* const* d_in, const int* in_sizes, int n_in,
                              void* d_out, int out_size, void* d_ws, size_t ws_size,
                              hipStream_t stream)
{
    const float* hs    = (const float*)d_in[0];
    const float* amask = (const float*)d_in[1];
    const float* adj   = (const float*)d_in[2];
    const float* Wq    = (const float*)d_in[3];
    const float* bq    = (const float*)d_in[4];
    const float* Wk    = (const float*)d_in[5];
    const float* bk    = (const float*)d_in[6];
    const float* Wv    = (const float*)d_in[7];
    const float* bv    = (const float*)d_in[8];
    float* out = (float*)d_out;

    // workspace: Wb2 (3.54MB) | bits (5.53MB) | hsb (35.8MB + 16KB pad-row slack)
    char* ws = (char*)d_ws;
    bf16* Wb2 = (bf16*)ws;                                       // 2304*768*2 = 3,538,944
    unsigned long long* bits = (unsigned long long*)(ws + 3538944);
    bf16* hsb = (bf16*)(ws + 3538944 + 5529600);                 // 23296*768*2 = 35,782,656 (+slack)

    prep<<<dim3(CVT_BLOCKS + ROCR * NBS), 256, 0, stream>>>(hs, Wq, Wk, Wv, adj, hsb, Wb2, bits);
    fused_qkv_attn<<<dim3(NBS * NH), 768, 0, stream>>>(hsb, Wb2, bq, bk, bv, amask, bits, out);
}

// Round 20
// 202.298 us; speedup vs baseline: 1.0814x; 1.0814x over previous
//
#include <hip/hip_runtime.h>
#include <hip/hip_bf16.h>

// Problem constants
#define NBS   128
#define NF    182      // 20 text + 150 ocr/obj + 12 decode
#define NP    192      // padded N for MFMA tiling
#define DMODEL 768
#define NH    12
#define HDIM  64
#define SEQT  20
#define ROCR  150

typedef __attribute__((ext_vector_type(4))) float  f32x4;
typedef __attribute__((ext_vector_type(8))) short  s16x8;
typedef __attribute__((ext_vector_type(4))) unsigned int u32x4;
using bf16 = __hip_bfloat16;

#define SB()    __builtin_amdgcn_sched_barrier(0)
#define BAR()   __builtin_amdgcn_s_barrier()

// global->LDS direct copy, 16B per lane. LDS dest linear in lane (base+lane*16).
__device__ __forceinline__ void gload_lds16(const void* g, void* l) {
    auto gp = (const __attribute__((address_space(1))) unsigned int*)((unsigned long long)g);
    auto lp = (__attribute__((address_space(3))) unsigned int*)(unsigned int)((unsigned long long)l);
    __builtin_amdgcn_global_load_lds(gp, lp, 16, 0, 0);
}

// ---------------------------------------------------------------------------
// Kernel 0: PREP (convert + pack_adj merged).
// Blocks [0, 9600): fp32->bf16: hs -> hsb; Wq|Wk|Wv -> Wb2 per-head layout
//   (Wb2 row R = h*192 + which*64 + r0 holds W_which[h*64+r0][:]).
// Blocks [9600, 28800): pack spatial adjacency -> bitmask (b,12,150,3).
// ---------------------------------------------------------------------------
#define CVT_BLOCKS 9600
__global__ __launch_bounds__(256) void prep(
    const float* __restrict__ hs,
    const float* __restrict__ Wq, const float* __restrict__ Wk, const float* __restrict__ Wv,
    const float* __restrict__ adj,
    bf16* __restrict__ hsb, bf16* __restrict__ Wb2,
    unsigned long long* __restrict__ bits)
{
    __shared__ float tile[ROCR * NH];       // used by pack branch only
    if (blockIdx.x < CVT_BLOCKS) {
        const size_t HT = (size_t)NBS * NF * DMODEL / 8;        // 2,236,416
        const size_t WT = 3ull * DMODEL * DMODEL / 8;           // 221,184
        size_t i = (size_t)blockIdx.x * 256 + threadIdx.x;
        if (i >= HT + WT) return;
        const float* src; bf16* dst;
        if (i < HT) {
            size_t e = i * 8; src = hs + e; dst = hsb + e;
        } else {
            size_t e = (i - HT) * 8;
            int R = (int)(e / DMODEL), c = (int)(e % DMODEL);
            int h = R / 192, t2 = (R % 192) / 64, r0 = R % 64;
            src = (t2 == 0 ? Wq : t2 == 1 ? Wk : Wv) + (size_t)(h * 64 + r0) * DMODEL + c;
            dst = Wb2 + e;
        }
        float4 a = *reinterpret_cast<const float4*>(src);
        float4 b = *reinterpret_cast<const float4*>(src + 4);
        union { s16x8 v; bf16 h8[8]; } u;
        u.h8[0] = __float2bfloat16(a.x); u.h8[1] = __float2bfloat16(a.y);
        u.h8[2] = __float2bfloat16(a.z); u.h8[3] = __float2bfloat16(a.w);
        u.h8[4] = __float2bfloat16(b.x); u.h8[5] = __float2bfloat16(b.y);
        u.h8[6] = __float2bfloat16(b.z); u.h8[7] = __float2bfloat16(b.w);
        *reinterpret_cast<s16x8*>(dst) = u.v;
    } else {
        const int pb = blockIdx.x - CVT_BLOCKS;
        const int b = pb / ROCR, r = pb - b * ROCR;
        const int tid = threadIdx.x, lane = tid & 63, w = tid >> 6;
        const float* src = adj + ((size_t)b * ROCR + r) * (ROCR * NH);
        for (int i = tid; i < ROCR * NH; i += 256) tile[i] = src[i];
        __syncthreads();
        for (int c = w; c < NH * 3; c += 4) {
            int hh = c / 3, wd = c - hh * 3;
            int k = wd * 64 + lane;
            int j = k - SEQT;
            bool v = false;
            if (j >= 0 && j < ROCR) v = (tile[j * NH + hh] > 0.5f);
            unsigned long long m = __ballot(v);
            if (lane == 0) bits[(((size_t)b * NH + hh) * ROCR + r) * 3 + wd] = m;
        }
    }
}

// ---------------------------------------------------------------------------
// Kernel 2: FUSED per-(b,h) QKV-projection + attention.  (R18 best-verified)
// 4 waves x 96x96 GEMM tile, 3-deep gload_lds staging (vmcnt 12/6/0),
// single-pass epilogue -> Q(x0.125)/K/Vt all in LDS (aliased over staging),
// in-register-P attention (swapped QK^T, per-lane softmax, shuffle PV).
// R19's 12-wave retile raised occupancy (20->32%) but regressed (barrier
// overhead > occupancy gain) — reverted; this geometry is the local optimum.
// LDS map:
//   [0..24576)      staging buf0 -> K[192][64] swz after GEMM
//   [24576..49152)  staging buf1 -> Vt[64][192] swz after GEMM
//   [49152..73728)  staging buf2 -> Q[192][64] swz (x0.125) after GEMM
// ---------------------------------------------------------------------------
#define KO2   0
#define VTO2  24576
#define QO3   49152

__global__ __launch_bounds__(256, 2) void fused_qkv_attn(
    const bf16* __restrict__ hsb, const bf16* __restrict__ Wb2,
    const float* __restrict__ bq, const float* __restrict__ bk, const float* __restrict__ bv,
    const float* __restrict__ amask,
    const unsigned long long* __restrict__ bits,
    float* __restrict__ out)
{
    __shared__ char L[73728];
    const int tid  = threadIdx.x;
    const int lane = tid & 63;
    const int wid  = tid >> 6;
    const int wr = wid >> 1, wc = wid & 1;      // 2x2 wave grid, 96x96 each
    const int lm = lane & 15, lg = lane >> 4;

    // m204 XCD chunking (1536 = 8*192): 12 head-blocks of one b on one XCD.
    const int flat = blockIdx.x;
    const int wgid = (flat & 7) * 192 + (flat >> 3);
    const int b = wgid / NH, h = wgid - b * NH;

    float* obase = out + (size_t)b * NF * DMODEL + h * HDIM;

    // ---- aw: amask ballot words, per-wave registers (no LDS, no sync) ----
    unsigned long long aw0, aw1, aw2;
    {
        int k0 = lane, k1 = 64 + lane, k2 = 128 + lane;
        aw0 = __ballot(amask[b * NF + k0] == 0.0f);
        aw1 = __ballot(amask[b * NF + k1] == 0.0f);
        aw2 = __ballot((k2 < NF) && (amask[b * NF + k2] == 0.0f));
    }
    // decode output rows are exactly zero
    for (int i = tid; i < 12 * 64; i += 256)
        obase[(size_t)(170 + (i >> 6)) * DMODEL + (i & 63)] = 0.f;

    // ---- Phase G: GEMM (BK=32, 3-deep staging pipeline, vmcnt(12)) ----
    const char* gA = (const char*)(hsb + (size_t)b * NF * DMODEL);   // 192 rows (pad rows in slack)
    const char* gW = (const char*)(Wb2 + (size_t)h * 192 * DMODEL);

    f32x4 acc[6][6];
    #pragma unroll
    for (int i = 0; i < 6; ++i)
        #pragma unroll
        for (int j = 0; j < 6; ++j) acc[i][j] = (f32x4){0.f, 0.f, 0.f, 0.f};

    const int srow4 = tid >> 2, sch4 = tid & 3;

    auto ST = [&](int kt, int bsel) {
        char* dA = L + bsel * 24576;
        char* dW = dA + 12288;
        #pragma unroll
        for (int it = 0; it < 3; ++it) {
            int row = it * 64 + srow4;
            int lc = sch4 ^ ((row >> 1) & 3);
            size_t go = (size_t)row * 1536 + (size_t)kt * 64 + lc * 16;
            int o = row * 64 + sch4 * 16;
            gload_lds16(gA + go, dA + o);
            gload_lds16(gW + go, dW + o);
        }
    };
    auto CP = [&](int bsel) {
        const char* Ab = L + bsel * 24576;
        const char* Wp = Ab + 12288;
        s16x8 af[6], bf6[6];
        #pragma unroll
        for (int mi = 0; mi < 6; ++mi) {
            int r = 96 * wr + 16 * mi + lm;
            af[mi] = *reinterpret_cast<const s16x8*>(Ab + r * 64 + ((lg ^ ((r >> 1) & 3)) << 4));
        }
        #pragma unroll
        for (int ni = 0; ni < 6; ++ni) {
            int r = 96 * wc + 16 * ni + lm;
            bf6[ni] = *reinterpret_cast<const s16x8*>(Wp + r * 64 + ((lg ^ ((r >> 1) & 3)) << 4));
        }
        __builtin_amdgcn_s_setprio(1);
        #pragma unroll
        for (int mi = 0; mi < 6; ++mi)
            #pragma unroll
            for (int ni = 0; ni < 6; ++ni)
                acc[mi][ni] = __builtin_amdgcn_mfma_f32_16x16x32_bf16(af[mi], bf6[ni], acc[mi][ni], 0, 0, 0);
        __builtin_amdgcn_s_setprio(0);
    };

    ST(0, 0);
    ST(1, 1);
    ST(2, 2);
    for (int t = 0; t < 24; ++t) {
        if (t <= 21)      { asm volatile("s_waitcnt vmcnt(12)" ::: "memory"); }
        else if (t == 22) { asm volatile("s_waitcnt vmcnt(6)"  ::: "memory"); }
        else              { asm volatile("s_waitcnt vmcnt(0)"  ::: "memory"); }
        SB(); BAR(); SB();
        CP(t % 3);
        SB(); BAR();
        if (t + 3 < 24) ST(t + 3, t % 3);
    }
    BAR();   // all CP reads done before epilogue overwrites staging region

    // ---- epilogue (SINGLE PASS): acc+bias -> Q/K/Vt LDS ----
    float bias6[6];
    #pragma unroll
    for (int ni = 0; ni < 6; ++ni) {
        int c = 96 * wc + 16 * ni + lm;
        int whichc = c >> 6, cc = c & 63;
        const float* bp = (whichc == 0) ? bq : (whichc == 1) ? bk : bv;
        bias6[ni] = bp[h * 64 + cc];
    }
    #pragma unroll
    for (int mi = 0; mi < 6; ++mi) {
        #pragma unroll
        for (int ni = 0; ni < 6; ++ni) {
            int c = 96 * wc + 16 * ni + lm;
            int row0 = 96 * wr + 16 * mi + 4 * lg;
            if (c < 64) {
                // Q, pre-scaled by 1/8 (exact pow2 in bf16)
                #pragma unroll
                for (int j = 0; j < 4; ++j) {
                    int row = row0 + j;
                    bf16 hv = __float2bfloat16((acc[mi][ni][j] + bias6[ni]) * 0.125f);
                    *reinterpret_cast<unsigned short*>(L + QO3 + row * 128 + ((2 * c) ^ ((row & 7) << 4))) =
                        *reinterpret_cast<unsigned short*>(&hv);
                }
            } else if (c < 128) {
                int cc = c - 64;
                #pragma unroll
                for (int j = 0; j < 4; ++j) {
                    int row = row0 + j;
                    bf16 hv = __float2bfloat16(acc[mi][ni][j] + bias6[ni]);
                    *reinterpret_cast<unsigned short*>(L + KO2 + row * 128 + ((2 * cc) ^ ((row & 7) << 4))) =
                        *reinterpret_cast<unsigned short*>(&hv);
                }
            } else {
                int d = c - 128;
                if (row0 + 3 < NF) {
                    union { unsigned long long u8; bf16 h[4]; } pk;
                    pk.h[0] = __float2bfloat16(acc[mi][ni][0] + bias6[ni]);
                    pk.h[1] = __float2bfloat16(acc[mi][ni][1] + bias6[ni]);
                    pk.h[2] = __float2bfloat16(acc[mi][ni][2] + bias6[ni]);
                    pk.h[3] = __float2bfloat16(acc[mi][ni][3] + bias6[ni]);
                    *reinterpret_cast<unsigned long long*>(L + VTO2 + d * 384 + ((2 * row0) ^ ((d & 7) << 4))) = pk.u8;
                } else {
                    #pragma unroll
                    for (int j = 0; j < 4; ++j) {
                        int row = row0 + j;
                        if (row < NF) {
                            bf16 hv = __float2bfloat16(acc[mi][ni][j] + bias6[ni]);
                            *reinterpret_cast<unsigned short*>(L + VTO2 + d * 384 + ((2 * row) ^ ((d & 7) << 4))) =
                                *reinterpret_cast<unsigned short*>(&hv);
                        }
                    }
                }
            }
        }
    }
    // zero Vt pad keys 182..191 (only writer of these addresses -> race-free)
    for (int i = tid; i < 64 * 10; i += 256) {
        int d = i / 10, k2 = NF + (i - d * 10);
        *reinterpret_cast<unsigned short*>(L + VTO2 + d * 384 + ((2 * k2) ^ ((d & 7) << 4))) = 0;
    }
    __syncthreads();

    // ---- Q-preload from LDS (verified addressing) ----
    s16x8 qf[3][2];
    #pragma unroll
    for (int bi = 0; bi < 3; ++bi) {
        int band = wid + 4 * bi;
        int qrow = ((band < 11) ? band * 16 : 0) + lm;      // safe dummy for band>=11
        const char* qb = L + QO3 + qrow * 128;
        int sq = (qrow & 7) << 4;
        qf[bi][0] = *reinterpret_cast<const s16x8*>(qb + ((lg * 16) ^ sq));
        qf[bi][1] = *reinterpret_cast<const s16x8*>(qb + ((64 + lg * 16) ^ sq));
    }

    // ---- Phase A: attention, P fully in-register (verified body) ----
    const unsigned long long* bbase = bits + ((size_t)b * NH + h) * ROCR * 3;
    const unsigned long long DEC = 0xFFFull << 42;          // keys 170..181

    #pragma unroll
    for (int bi = 0; bi < 3; ++bi) {
        const int band = wid + 4 * bi;
        if (band >= 11) continue;
        const int q0 = band * 16;

        // masks for this lane's q-row, straight from global bits (L2-hot)
        const int qrow = q0 + lm;
        unsigned long long mw0, mw1, mw2;
        if (qrow < SEQT) {
            mw0 = 0; mw1 = 0; mw2 = DEC & aw2;
        } else {
            const unsigned long long* bp = bbase + (size_t)(qrow - SEQT) * 3;
            mw0 = bp[0] & aw0;
            mw1 = bp[1] & aw1;
            mw2 = (bp[2] | DEC) & aw2;
        }

        // swapped QK^T: sacc[t][j] = S[key=16t+4lg+j][qrow=q0+lm] (pre-scaled)
        f32x4 sacc[12];
        #pragma unroll
        for (int t = 0; t < 12; ++t) sacc[t] = (f32x4){0.f, 0.f, 0.f, 0.f};
        #pragma unroll
        for (int t = 0; t < 12; ++t) {
            int key = t * 16 + lm;
            const char* kb = L + KO2 + key * 128;
            int sw = (key & 7) << 4;
            s16x8 kf0 = *reinterpret_cast<const s16x8*>(kb + ((lg * 16) ^ sw));
            s16x8 kf1 = *reinterpret_cast<const s16x8*>(kb + ((64 + lg * 16) ^ sw));
            sacc[t] = __builtin_amdgcn_mfma_f32_16x16x32_bf16(kf0, qf[bi][0], sacc[t], 0, 0, 0);
            sacc[t] = __builtin_amdgcn_mfma_f32_16x16x32_bf16(kf1, qf[bi][1], sacc[t], 0, 0, 0);
        }

        // mask + per-lane softmax (this lane owns one q-row)
        float mx = -3.0e38f;
        #pragma unroll
        for (int t = 0; t < 12; ++t) {
            unsigned long long w = (t < 4) ? mw0 : (t < 8) ? mw1 : mw2;
            #pragma unroll
            for (int j = 0; j < 4; ++j) {
                int sh = ((t & 3) << 4) + 4 * lg + j;
                float s = sacc[t][j];
                s = ((w >> sh) & 1ull) ? s : -3.0e38f;
                sacc[t][j] = s;
                mx = fmaxf(mx, s);
            }
        }
        mx = fmaxf(mx, __shfl_xor(mx, 16));
        mx = fmaxf(mx, __shfl_xor(mx, 32));
        float sum = 0.f;
        #pragma unroll
        for (int t = 0; t < 12; ++t)
            #pragma unroll
            for (int j = 0; j < 4; ++j) {
                float e = (sacc[t][j] > -1.0e37f) ? __expf(sacc[t][j] - mx) : 0.f;
                sacc[t][j] = e;
                sum += e;
            }
        sum += __shfl_xor(sum, 16);
        sum += __shfl_xor(sum, 32);
        float scl = (mx > -1.0e37f) ? 1.0f / sum : 0.f;

        // pack P rows to bf16 dword pairs per tile
        unsigned int p0[12], p1[12];
        #pragma unroll
        for (int t = 0; t < 12; ++t) {
            bf16 b0 = __float2bfloat16(sacc[t][0] * scl);
            bf16 b1 = __float2bfloat16(sacc[t][1] * scl);
            bf16 b2 = __float2bfloat16(sacc[t][2] * scl);
            bf16 b3 = __float2bfloat16(sacc[t][3] * scl);
            p0[t] = (unsigned int)*reinterpret_cast<unsigned short*>(&b0)
                  | ((unsigned int)*reinterpret_cast<unsigned short*>(&b1) << 16);
            p1[t] = (unsigned int)*reinterpret_cast<unsigned short*>(&b2)
                  | ((unsigned int)*reinterpret_cast<unsigned short*>(&b3) << 16);
        }

        // PV: build A-frags by lane exchange; dest (lg,ks) = keys 32ks+8lg+0..7
        f32x4 oacc[4];
        #pragma unroll
        for (int t = 0; t < 4; ++t) oacc[t] = (f32x4){0.f, 0.f, 0.f, 0.f};
        const bool hi = (lg & 1);
        #pragma unroll
        for (int ks = 0; ks < 6; ++ks) {
            unsigned int A0 = p0[2 * ks],     A1 = p1[2 * ks];
            unsigned int B0 = p0[2 * ks + 1], B1 = p1[2 * ks + 1];
            unsigned int u0 = __shfl_xor(A0, 16), u1 = __shfl_xor(A1, 16);
            unsigned int v0 = __shfl_xor(B0, 16), v1 = __shfl_xor(B1, 16);
            unsigned int hA0 = hi ? u0 : A0, hA1 = hi ? u1 : A1;
            unsigned int hA2 = hi ? A0 : u0, hA3 = hi ? A1 : u1;
            unsigned int hB0 = hi ? v0 : B0, hB1 = hi ? v1 : B1;
            unsigned int hB2 = hi ? B0 : v0, hB3 = hi ? B1 : v1;
            unsigned int xA0 = __shfl_xor(hA0, 32), xA1 = __shfl_xor(hA1, 32);
            unsigned int xA2 = __shfl_xor(hA2, 32), xA3 = __shfl_xor(hA3, 32);
            unsigned int xB0 = __shfl_xor(hB0, 32), xB1 = __shfl_xor(hB1, 32);
            unsigned int xB2 = __shfl_xor(hB2, 32), xB3 = __shfl_xor(hB3, 32);
            u32x4 f;
            if (lg == 0)      f = (u32x4){hA0, hA1, hA2, hA3};
            else if (lg == 1) f = (u32x4){xA0, xA1, xA2, xA3};
            else if (lg == 2) f = (u32x4){xB0, xB1, xB2, xB3};
            else              f = (u32x4){hB0, hB1, hB2, hB3};
            s16x8 pa;
            __builtin_memcpy(&pa, &f, 16);
            #pragma unroll
            for (int t2 = 0; t2 < 4; ++t2) {
                int d = t2 * 16 + lm;
                s16x8 vf = *reinterpret_cast<const s16x8*>(L + VTO2 + d * 384 + ((ks * 64 + lg * 16) ^ ((d & 7) << 4)));
                oacc[t2] = __builtin_amdgcn_mfma_f32_16x16x32_bf16(pa, vf, oacc[t2], 0, 0, 0);
            }
        }
        #pragma unroll
        for (int j = 0; j < 4; ++j) {
            int row = q0 + lg * 4 + j;
            if (row < 170) {
                #pragma unroll
                for (int t2 = 0; t2 < 4; ++t2)
                    obase[(size_t)row * DMODEL + t2 * 16 + lm] = oacc[t2][j];
            }
        }
    }
}

// ---------------------------------------------------------------------------
extern "C" void kernel_launch(void* const* d_in, const int* in_sizes, int n_in,
                              void* d_out, int out_size, void* d_ws, size_t ws_size,
                              hipStream_t stream)
{
    const float* hs    = (const float*)d_in[0];
    const float* amask = (const float*)d_in[1];
    const float* adj   = (const float*)d_in[2];
    const float* Wq    = (const float*)d_in[3];
    const float* bq    = (const float*)d_in[4];
    const float* Wk    = (const float*)d_in[5];
    const float* bk    = (const float*)d_in[6];
    const float* Wv    = (const float*)d_in[7];
    const float* bv    = (const float*)d_in[8];
    float* out = (float*)d_out;

    // workspace: Wb2 (3.54MB) | bits (5.53MB) | hsb (35.8MB + 16KB pad-row slack)
    char* ws = (char*)d_ws;
    bf16* Wb2 = (bf16*)ws;                                       // 2304*768*2 = 3,538,944
    unsigned long long* bits = (unsigned long long*)(ws + 3538944);
    bf16* hsb = (bf16*)(ws + 3538944 + 5529600);                 // 23296*768*2 = 35,782,656 (+slack)

    prep<<<dim3(CVT_BLOCKS + ROCR * NBS), 256, 0, stream>>>(hs, Wq, Wk, Wv, adj, hsb, Wb2, bits);
    fused_qkv_attn<<<dim3(NBS * NH), 256, 0, stream>>>(hsb, Wb2, bq, bk, bv, amask, bits, out);
}

// Round 21
// 198.281 us; speedup vs baseline: 1.1033x; 1.0203x over previous
//
#include <hip/hip_runtime.h>
#include <hip/hip_bf16.h>

// Problem constants
#define NBS   128
#define NF    182      // 20 text + 150 ocr/obj + 12 decode
#define NP    192      // padded N for MFMA tiling
#define DMODEL 768
#define NH    12
#define HDIM  64
#define SEQT  20
#define ROCR  150

typedef __attribute__((ext_vector_type(4))) float  f32x4;
typedef __attribute__((ext_vector_type(8))) short  s16x8;
typedef __attribute__((ext_vector_type(4))) unsigned int u32x4;
using bf16 = __hip_bfloat16;

#define SB()    __builtin_amdgcn_sched_barrier(0)
#define BAR()   __builtin_amdgcn_s_barrier()

// global->LDS direct copy, 16B per lane. LDS dest linear in lane (base+lane*16).
__device__ __forceinline__ void gload_lds16(const void* g, void* l) {
    auto gp = (const __attribute__((address_space(1))) unsigned int*)((unsigned long long)g);
    auto lp = (__attribute__((address_space(3))) unsigned int*)(unsigned int)((unsigned long long)l);
    __builtin_amdgcn_global_load_lds(gp, lp, 16, 0, 0);
}

// ---------------------------------------------------------------------------
// Kernel 0: PREP (convert + pack_adj merged).
// Blocks [0, 9600): fp32->bf16: hs -> hsb; Wq|Wk|Wv -> Wb2 per-head layout
//   (Wb2 row R = h*192 + which*64 + r0 holds W_which[h*64+r0][:]).
// Blocks [9600, 28800): pack spatial adjacency -> bitmask (b,12,150,3).
// ---------------------------------------------------------------------------
#define CVT_BLOCKS 9600
__global__ __launch_bounds__(256) void prep(
    const float* __restrict__ hs,
    const float* __restrict__ Wq, const float* __restrict__ Wk, const float* __restrict__ Wv,
    const float* __restrict__ adj,
    bf16* __restrict__ hsb, bf16* __restrict__ Wb2,
    unsigned long long* __restrict__ bits)
{
    __shared__ float tile[ROCR * NH];       // used by pack branch only
    if (blockIdx.x < CVT_BLOCKS) {
        const size_t HT = (size_t)NBS * NF * DMODEL / 8;        // 2,236,416
        const size_t WT = 3ull * DMODEL * DMODEL / 8;           // 221,184
        size_t i = (size_t)blockIdx.x * 256 + threadIdx.x;
        if (i >= HT + WT) return;
        const float* src; bf16* dst;
        if (i < HT) {
            size_t e = i * 8; src = hs + e; dst = hsb + e;
        } else {
            size_t e = (i - HT) * 8;
            int R = (int)(e / DMODEL), c = (int)(e % DMODEL);
            int h = R / 192, t2 = (R % 192) / 64, r0 = R % 64;
            src = (t2 == 0 ? Wq : t2 == 1 ? Wk : Wv) + (size_t)(h * 64 + r0) * DMODEL + c;
            dst = Wb2 + e;
        }
        float4 a = *reinterpret_cast<const float4*>(src);
        float4 b = *reinterpret_cast<const float4*>(src + 4);
        union { s16x8 v; bf16 h8[8]; } u;
        u.h8[0] = __float2bfloat16(a.x); u.h8[1] = __float2bfloat16(a.y);
        u.h8[2] = __float2bfloat16(a.z); u.h8[3] = __float2bfloat16(a.w);
        u.h8[4] = __float2bfloat16(b.x); u.h8[5] = __float2bfloat16(b.y);
        u.h8[6] = __float2bfloat16(b.z); u.h8[7] = __float2bfloat16(b.w);
        *reinterpret_cast<s16x8*>(dst) = u.v;
    } else {
        const int pb = blockIdx.x - CVT_BLOCKS;
        const int b = pb / ROCR, r = pb - b * ROCR;
        const int tid = threadIdx.x, lane = tid & 63, w = tid >> 6;
        const float* src = adj + ((size_t)b * ROCR + r) * (ROCR * NH);
        for (int i = tid; i < ROCR * NH; i += 256) tile[i] = src[i];
        __syncthreads();
        for (int c = w; c < NH * 3; c += 4) {
            int hh = c / 3, wd = c - hh * 3;
            int k = wd * 64 + lane;
            int j = k - SEQT;
            bool v = false;
            if (j >= 0 && j < ROCR) v = (tile[j * NH + hh] > 0.5f);
            unsigned long long m = __ballot(v);
            if (lane == 0) bits[(((size_t)b * NH + hh) * ROCR + r) * 3 + wd] = m;
        }
    }
}

// ---------------------------------------------------------------------------
// Kernel 2: FUSED per-(b,h) QKV-projection + attention.  (R18 base)
// This round: ONE barrier per K-iteration (was two). 3-buffer ring with
// ST-before-CP: ST(t+2) -> buf((t+2)%3), which was consumed at CP(t-1); all
// waves finished CP(t-1) before crossing this iteration's barrier (their
// ds_reads are lgkm-drained by the consuming MFMAs), so the post-CP barrier
// is unnecessary. Flight time per tile unchanged (~2 compute phases);
// barrier count 48 -> 25. vmcnt(6) readies tile t (tiles t,t+1 outstanding).
// LDS map:
//   [0..24576)      staging buf0 -> K[192][64] swz after GEMM
//   [24576..49152)  staging buf1 -> Vt[64][192] swz after GEMM
//   [49152..73728)  staging buf2 -> Q[192][64] swz (x0.125) after GEMM
// ---------------------------------------------------------------------------
#define KO2   0
#define VTO2  24576
#define QO3   49152

__global__ __launch_bounds__(256, 2) void fused_qkv_attn(
    const bf16* __restrict__ hsb, const bf16* __restrict__ Wb2,
    const float* __restrict__ bq, const float* __restrict__ bk, const float* __restrict__ bv,
    const float* __restrict__ amask,
    const unsigned long long* __restrict__ bits,
    float* __restrict__ out)
{
    __shared__ char L[73728];
    const int tid  = threadIdx.x;
    const int lane = tid & 63;
    const int wid  = tid >> 6;
    const int wr = wid >> 1, wc = wid & 1;      // 2x2 wave grid, 96x96 each
    const int lm = lane & 15, lg = lane >> 4;

    // m204 XCD chunking (1536 = 8*192): 12 head-blocks of one b on one XCD.
    const int flat = blockIdx.x;
    const int wgid = (flat & 7) * 192 + (flat >> 3);
    const int b = wgid / NH, h = wgid - b * NH;

    float* obase = out + (size_t)b * NF * DMODEL + h * HDIM;

    // ---- aw: amask ballot words, per-wave registers (no LDS, no sync) ----
    unsigned long long aw0, aw1, aw2;
    {
        int k0 = lane, k1 = 64 + lane, k2 = 128 + lane;
        aw0 = __ballot(amask[b * NF + k0] == 0.0f);
        aw1 = __ballot(amask[b * NF + k1] == 0.0f);
        aw2 = __ballot((k2 < NF) && (amask[b * NF + k2] == 0.0f));
    }
    // decode output rows are exactly zero
    for (int i = tid; i < 12 * 64; i += 256)
        obase[(size_t)(170 + (i >> 6)) * DMODEL + (i & 63)] = 0.f;

    // ---- Phase G: GEMM (BK=32, 3-buffer ring, 1 barrier/iter, vmcnt(6)) ----
    const char* gA = (const char*)(hsb + (size_t)b * NF * DMODEL);   // 192 rows (pad rows in slack)
    const char* gW = (const char*)(Wb2 + (size_t)h * 192 * DMODEL);

    f32x4 acc[6][6];
    #pragma unroll
    for (int i = 0; i < 6; ++i)
        #pragma unroll
        for (int j = 0; j < 6; ++j) acc[i][j] = (f32x4){0.f, 0.f, 0.f, 0.f};

    const int srow4 = tid >> 2, sch4 = tid & 3;

    auto ST = [&](int kt, int bsel) {
        char* dA = L + bsel * 24576;
        char* dW = dA + 12288;
        #pragma unroll
        for (int it = 0; it < 3; ++it) {
            int row = it * 64 + srow4;
            int lc = sch4 ^ ((row >> 1) & 3);
            size_t go = (size_t)row * 1536 + (size_t)kt * 64 + lc * 16;
            int o = row * 64 + sch4 * 16;
            gload_lds16(gA + go, dA + o);
            gload_lds16(gW + go, dW + o);
        }
    };
    auto CP = [&](int bsel) {
        const char* Ab = L + bsel * 24576;
        const char* Wp = Ab + 12288;
        s16x8 af[6], bf6[6];
        #pragma unroll
        for (int mi = 0; mi < 6; ++mi) {
            int r = 96 * wr + 16 * mi + lm;
            af[mi] = *reinterpret_cast<const s16x8*>(Ab + r * 64 + ((lg ^ ((r >> 1) & 3)) << 4));
        }
        #pragma unroll
        for (int ni = 0; ni < 6; ++ni) {
            int r = 96 * wc + 16 * ni + lm;
            bf6[ni] = *reinterpret_cast<const s16x8*>(Wp + r * 64 + ((lg ^ ((r >> 1) & 3)) << 4));
        }
        __builtin_amdgcn_s_setprio(1);
        #pragma unroll
        for (int mi = 0; mi < 6; ++mi)
            #pragma unroll
            for (int ni = 0; ni < 6; ++ni)
                acc[mi][ni] = __builtin_amdgcn_mfma_f32_16x16x32_bf16(af[mi], bf6[ni], acc[mi][ni], 0, 0, 0);
        __builtin_amdgcn_s_setprio(0);
    };

    // prologue: two tiles in flight
    ST(0, 0);
    ST(1, 1);
    for (int t = 0; t < 24; ++t) {
        // wait tile t landed (tiles t, t+1 outstanding -> allow 6 loads in flight)
        if (t < 23) { asm volatile("s_waitcnt vmcnt(6)" ::: "memory"); }
        else        { asm volatile("s_waitcnt vmcnt(0)" ::: "memory"); }
        SB(); BAR(); SB();
        // ST into buf consumed at CP(t-1): all waves past it (they crossed BAR)
        if (t + 2 < 24) ST(t + 2, (t + 2) % 3);
        CP(t % 3);
        SB();
    }
    BAR();   // all CP reads done before epilogue overwrites staging region

    // ---- epilogue (SINGLE PASS): acc+bias -> Q/K/Vt LDS ----
    float bias6[6];
    #pragma unroll
    for (int ni = 0; ni < 6; ++ni) {
        int c = 96 * wc + 16 * ni + lm;
        int whichc = c >> 6, cc = c & 63;
        const float* bp = (whichc == 0) ? bq : (whichc == 1) ? bk : bv;
        bias6[ni] = bp[h * 64 + cc];
    }
    #pragma unroll
    for (int mi = 0; mi < 6; ++mi) {
        #pragma unroll
        for (int ni = 0; ni < 6; ++ni) {
            int c = 96 * wc + 16 * ni + lm;
            int row0 = 96 * wr + 16 * mi + 4 * lg;
            if (c < 64) {
                // Q, pre-scaled by 1/8 (exact pow2 in bf16)
                #pragma unroll
                for (int j = 0; j < 4; ++j) {
                    int row = row0 + j;
                    bf16 hv = __float2bfloat16((acc[mi][ni][j] + bias6[ni]) * 0.125f);
                    *reinterpret_cast<unsigned short*>(L + QO3 + row * 128 + ((2 * c) ^ ((row & 7) << 4))) =
                        *reinterpret_cast<unsigned short*>(&hv);
                }
            } else if (c < 128) {
                int cc = c - 64;
                #pragma unroll
                for (int j = 0; j < 4; ++j) {
                    int row = row0 + j;
                    bf16 hv = __float2bfloat16(acc[mi][ni][j] + bias6[ni]);
                    *reinterpret_cast<unsigned short*>(L + KO2 + row * 128 + ((2 * cc) ^ ((row & 7) << 4))) =
                        *reinterpret_cast<unsigned short*>(&hv);
                }
            } else {
                int d = c - 128;
                if (row0 + 3 < NF) {
                    union { unsigned long long u8; bf16 h[4]; } pk;
                    pk.h[0] = __float2bfloat16(acc[mi][ni][0] + bias6[ni]);
                    pk.h[1] = __float2bfloat16(acc[mi][ni][1] + bias6[ni]);
                    pk.h[2] = __float2bfloat16(acc[mi][ni][2] + bias6[ni]);
                    pk.h[3] = __float2bfloat16(acc[mi][ni][3] + bias6[ni]);
                    *reinterpret_cast<unsigned long long*>(L + VTO2 + d * 384 + ((2 * row0) ^ ((d & 7) << 4))) = pk.u8;
                } else {
                    #pragma unroll
                    for (int j = 0; j < 4; ++j) {
                        int row = row0 + j;
                        if (row < NF) {
                            bf16 hv = __float2bfloat16(acc[mi][ni][j] + bias6[ni]);
                            *reinterpret_cast<unsigned short*>(L + VTO2 + d * 384 + ((2 * row) ^ ((d & 7) << 4))) =
                                *reinterpret_cast<unsigned short*>(&hv);
                        }
                    }
                }
            }
        }
    }
    // zero Vt pad keys 182..191 (only writer of these addresses -> race-free)
    for (int i = tid; i < 64 * 10; i += 256) {
        int d = i / 10, k2 = NF + (i - d * 10);
        *reinterpret_cast<unsigned short*>(L + VTO2 + d * 384 + ((2 * k2) ^ ((d & 7) << 4))) = 0;
    }
    __syncthreads();

    // ---- Q-preload from LDS (verified addressing) ----
    s16x8 qf[3][2];
    #pragma unroll
    for (int bi = 0; bi < 3; ++bi) {
        int band = wid + 4 * bi;
        int qrow = ((band < 11) ? band * 16 : 0) + lm;      // safe dummy for band>=11
        const char* qb = L + QO3 + qrow * 128;
        int sq = (qrow & 7) << 4;
        qf[bi][0] = *reinterpret_cast<const s16x8*>(qb + ((lg * 16) ^ sq));
        qf[bi][1] = *reinterpret_cast<const s16x8*>(qb + ((64 + lg * 16) ^ sq));
    }

    // ---- Phase A: attention, P fully in-register (verified body) ----
    const unsigned long long* bbase = bits + ((size_t)b * NH + h) * ROCR * 3;
    const unsigned long long DEC = 0xFFFull << 42;          // keys 170..181

    #pragma unroll
    for (int bi = 0; bi < 3; ++bi) {
        const int band = wid + 4 * bi;
        if (band >= 11) continue;
        const int q0 = band * 16;

        // masks for this lane's q-row, straight from global bits (L2-hot)
        const int qrow = q0 + lm;
        unsigned long long mw0, mw1, mw2;
        if (qrow < SEQT) {
            mw0 = 0; mw1 = 0; mw2 = DEC & aw2;
        } else {
            const unsigned long long* bp = bbase + (size_t)(qrow - SEQT) * 3;
            mw0 = bp[0] & aw0;
            mw1 = bp[1] & aw1;
            mw2 = (bp[2] | DEC) & aw2;
        }

        // swapped QK^T: sacc[t][j] = S[key=16t+4lg+j][qrow=q0+lm] (pre-scaled)
        f32x4 sacc[12];
        #pragma unroll
        for (int t = 0; t < 12; ++t) sacc[t] = (f32x4){0.f, 0.f, 0.f, 0.f};
        #pragma unroll
        for (int t = 0; t < 12; ++t) {
            int key = t * 16 + lm;
            const char* kb = L + KO2 + key * 128;
            int sw = (key & 7) << 4;
            s16x8 kf0 = *reinterpret_cast<const s16x8*>(kb + ((lg * 16) ^ sw));
            s16x8 kf1 = *reinterpret_cast<const s16x8*>(kb + ((64 + lg * 16) ^ sw));
            sacc[t] = __builtin_amdgcn_mfma_f32_16x16x32_bf16(kf0, qf[bi][0], sacc[t], 0, 0, 0);
            sacc[t] = __builtin_amdgcn_mfma_f32_16x16x32_bf16(kf1, qf[bi][1], sacc[t], 0, 0, 0);
        }

        // mask + per-lane softmax (this lane owns one q-row)
        float mx = -3.0e38f;
        #pragma unroll
        for (int t = 0; t < 12; ++t) {
            unsigned long long w = (t < 4) ? mw0 : (t < 8) ? mw1 : mw2;
            #pragma unroll
            for (int j = 0; j < 4; ++j) {
                int sh = ((t & 3) << 4) + 4 * lg + j;
                float s = sacc[t][j];
                s = ((w >> sh) & 1ull) ? s : -3.0e38f;
                sacc[t][j] = s;
                mx = fmaxf(mx, s);
            }
        }
        mx = fmaxf(mx, __shfl_xor(mx, 16));
        mx = fmaxf(mx, __shfl_xor(mx, 32));
        float sum = 0.f;
        #pragma unroll
        for (int t = 0; t < 12; ++t)
            #pragma unroll
            for (int j = 0; j < 4; ++j) {
                float e = (sacc[t][j] > -1.0e37f) ? __expf(sacc[t][j] - mx) : 0.f;
                sacc[t][j] = e;
                sum += e;
            }
        sum += __shfl_xor(sum, 16);
        sum += __shfl_xor(sum, 32);
        float scl = (mx > -1.0e37f) ? 1.0f / sum : 0.f;

        // pack P rows to bf16 dword pairs per tile
        unsigned int p0[12], p1[12];
        #pragma unroll
        for (int t = 0; t < 12; ++t) {
            bf16 b0 = __float2bfloat16(sacc[t][0] * scl);
            bf16 b1 = __float2bfloat16(sacc[t][1] * scl);
            bf16 b2 = __float2bfloat16(sacc[t][2] * scl);
            bf16 b3 = __float2bfloat16(sacc[t][3] * scl);
            p0[t] = (unsigned int)*reinterpret_cast<unsigned short*>(&b0)
                  | ((unsigned int)*reinterpret_cast<unsigned short*>(&b1) << 16);
            p1[t] = (unsigned int)*reinterpret_cast<unsigned short*>(&b2)
                  | ((unsigned int)*reinterpret_cast<unsigned short*>(&b3) << 16);
        }

        // PV: build A-frags by lane exchange; dest (lg,ks) = keys 32ks+8lg+0..7
        f32x4 oacc[4];
        #pragma unroll
        for (int t = 0; t < 4; ++t) oacc[t] = (f32x4){0.f, 0.f, 0.f, 0.f};
        const bool hi = (lg & 1);
        #pragma unroll
        for (int ks = 0; ks < 6; ++ks) {
            unsigned int A0 = p0[2 * ks],     A1 = p1[2 * ks];
            unsigned int B0 = p0[2 * ks + 1], B1 = p1[2 * ks + 1];
            unsigned int u0 = __shfl_xor(A0, 16), u1 = __shfl_xor(A1, 16);
            unsigned int v0 = __shfl_xor(B0, 16), v1 = __shfl_xor(B1, 16);
            unsigned int hA0 = hi ? u0 : A0, hA1 = hi ? u1 : A1;
            unsigned int hA2 = hi ? A0 : u0, hA3 = hi ? A1 : u1;
            unsigned int hB0 = hi ? v0 : B0, hB1 = hi ? v1 : B1;
            unsigned int hB2 = hi ? B0 : v0, hB3 = hi ? B1 : v1;
            unsigned int xA0 = __shfl_xor(hA0, 32), xA1 = __shfl_xor(hA1, 32);
            unsigned int xA2 = __shfl_xor(hA2, 32), xA3 = __shfl_xor(hA3, 32);
            unsigned int xB0 = __shfl_xor(hB0, 32), xB1 = __shfl_xor(hB1, 32);
            unsigned int xB2 = __shfl_xor(hB2, 32), xB3 = __shfl_xor(hB3, 32);
            u32x4 f;
            if (lg == 0)      f = (u32x4){hA0, hA1, hA2, hA3};
            else if (lg == 1) f = (u32x4){xA0, xA1, xA2, xA3};
            else if (lg == 2) f = (u32x4){xB0, xB1, xB2, xB3};
            else              f = (u32x4){hB0, hB1, hB2, hB3};
            s16x8 pa;
            __builtin_memcpy(&pa, &f, 16);
            #pragma unroll
            for (int t2 = 0; t2 < 4; ++t2) {
                int d = t2 * 16 + lm;
                s16x8 vf = *reinterpret_cast<const s16x8*>(L + VTO2 + d * 384 + ((ks * 64 + lg * 16) ^ ((d & 7) << 4)));
                oacc[t2] = __builtin_amdgcn_mfma_f32_16x16x32_bf16(pa, vf, oacc[t2], 0, 0, 0);
            }
        }
        #pragma unroll
        for (int j = 0; j < 4; ++j) {
            int row = q0 + lg * 4 + j;
            if (row < 170) {
                #pragma unroll
                for (int t2 = 0; t2 < 4; ++t2)
                    obase[(size_t)row * DMODEL + t2 * 16 + lm] = oacc[t2][j];
            }
        }
    }
}

// ---------------------------------------------------------------------------
extern "C" void kernel_launch(void* const* d_in, const int* in_sizes, int n_in,
                              void* d_out, int out_size, void* d_ws, size_t ws_size,
                              hipStream_t stream)
{
    const float* hs    = (const float*)d_in[0];
    const float* amask = (const float*)d_in[1];
    const float* adj   = (const float*)d_in[2];
    const float* Wq    = (const float*)d_in[3];
    const float* bq    = (const float*)d_in[4];
    const float* Wk    = (const float*)d_in[5];
    const float* bk    = (const float*)d_in[6];
    const float* Wv    = (const float*)d_in[7];
    const float* bv    = (const float*)d_in[8];
    float* out = (float*)d_out;

    // workspace: Wb2 (3.54MB) | bits (5.53MB) | hsb (35.8MB + 16KB pad-row slack)
    char* ws = (char*)d_ws;
    bf16* Wb2 = (bf16*)ws;                                       // 2304*768*2 = 3,538,944
    unsigned long long* bits = (unsigned long long*)(ws + 3538944);
    bf16* hsb = (bf16*)(ws + 3538944 + 5529600);                 // 23296*768*2 = 35,782,656 (+slack)

    prep<<<dim3(CVT_BLOCKS + ROCR * NBS), 256, 0, stream>>>(hs, Wq, Wk, Wv, adj, hsb, Wb2, bits);
    fused_qkv_attn<<<dim3(NBS * NH), 256, 0, stream>>>(hsb, Wb2, bq, bk, bv, amask, bits, out);
}

// Round 22
// 198.091 us; speedup vs baseline: 1.1044x; 1.0010x over previous
//
#include <hip/hip_runtime.h>
#include <hip/hip_bf16.h>

// Problem constants
#define NBS   128
#define NF    182      // 20 text + 150 ocr/obj + 12 decode
#define NP    192      // padded N for MFMA tiling
#define DMODEL 768
#define NH    12
#define HDIM  64
#define SEQT  20
#define ROCR  150

typedef __attribute__((ext_vector_type(4))) float  f32x4;
typedef __attribute__((ext_vector_type(8))) short  s16x8;
typedef __attribute__((ext_vector_type(4))) unsigned int u32x4;
using bf16 = __hip_bfloat16;

#define SB()    __builtin_amdgcn_sched_barrier(0)
#define BAR()   __builtin_amdgcn_s_barrier()

// global->LDS direct copy, 16B per lane. LDS dest linear in lane (base+lane*16).
__device__ __forceinline__ void gload_lds16(const void* g, void* l) {
    auto gp = (const __attribute__((address_space(1))) unsigned int*)((unsigned long long)g);
    auto lp = (__attribute__((address_space(3))) unsigned int*)(unsigned int)((unsigned long long)l);
    __builtin_amdgcn_global_load_lds(gp, lp, 16, 0, 0);
}

// ---------------------------------------------------------------------------
// Kernel 0: PREP (convert + pack_adj merged).
// Blocks [0, 9600): fp32->bf16: hs -> hsb; Wq|Wk|Wv -> Wb2 per-head layout
//   (Wb2 row R = h*192 + which*64 + r0 holds W_which[h*64+r0][:]).
// Blocks [9600, 28800): pack spatial adjacency -> bitmask (b,12,150,3).
// ---------------------------------------------------------------------------
#define CVT_BLOCKS 9600
__global__ __launch_bounds__(256) void prep(
    const float* __restrict__ hs,
    const float* __restrict__ Wq, const float* __restrict__ Wk, const float* __restrict__ Wv,
    const float* __restrict__ adj,
    bf16* __restrict__ hsb, bf16* __restrict__ Wb2,
    unsigned long long* __restrict__ bits)
{
    __shared__ float tile[ROCR * NH];       // used by pack branch only
    if (blockIdx.x < CVT_BLOCKS) {
        const size_t HT = (size_t)NBS * NF * DMODEL / 8;        // 2,236,416
        const size_t WT = 3ull * DMODEL * DMODEL / 8;           // 221,184
        size_t i = (size_t)blockIdx.x * 256 + threadIdx.x;
        if (i >= HT + WT) return;
        const float* src; bf16* dst;
        if (i < HT) {
            size_t e = i * 8; src = hs + e; dst = hsb + e;
        } else {
            size_t e = (i - HT) * 8;
            int R = (int)(e / DMODEL), c = (int)(e % DMODEL);
            int h = R / 192, t2 = (R % 192) / 64, r0 = R % 64;
            src = (t2 == 0 ? Wq : t2 == 1 ? Wk : Wv) + (size_t)(h * 64 + r0) * DMODEL + c;
            dst = Wb2 + e;
        }
        float4 a = *reinterpret_cast<const float4*>(src);
        float4 b = *reinterpret_cast<const float4*>(src + 4);
        union { s16x8 v; bf16 h8[8]; } u;
        u.h8[0] = __float2bfloat16(a.x); u.h8[1] = __float2bfloat16(a.y);
        u.h8[2] = __float2bfloat16(a.z); u.h8[3] = __float2bfloat16(a.w);
        u.h8[4] = __float2bfloat16(b.x); u.h8[5] = __float2bfloat16(b.y);
        u.h8[6] = __float2bfloat16(b.z); u.h8[7] = __float2bfloat16(b.w);
        *reinterpret_cast<s16x8*>(dst) = u.v;
    } else {
        const int pb = blockIdx.x - CVT_BLOCKS;
        const int b = pb / ROCR, r = pb - b * ROCR;
        const int tid = threadIdx.x, lane = tid & 63, w = tid >> 6;
        const float* src = adj + ((size_t)b * ROCR + r) * (ROCR * NH);
        for (int i = tid; i < ROCR * NH; i += 256) tile[i] = src[i];
        __syncthreads();
        for (int c = w; c < NH * 3; c += 4) {
            int hh = c / 3, wd = c - hh * 3;
            int k = wd * 64 + lane;
            int j = k - SEQT;
            bool v = false;
            if (j >= 0 && j < ROCR) v = (tile[j * NH + hh] > 0.5f);
            unsigned long long m = __ballot(v);
            if (lane == 0) bits[(((size_t)b * NH + hh) * ROCR + r) * 3 + wd] = m;
        }
    }
}

// ---------------------------------------------------------------------------
// Kernel 2: FUSED per-(b,h) QKV-projection + attention.  (best-verified)
// 4 waves x 96x96 GEMM tile; BK=32; 3-buffer ring, ONE barrier per K-iter
// (ST(t+2) overwrites the buffer consumed at CP(t-1) — all waves crossed
// this iteration's barrier after those reads); counted vmcnt(6).
// Single-pass epilogue -> Q(x0.125)/K/Vt all in LDS (aliased over staging);
// in-register-P attention (swapped QK^T, per-lane softmax, shuffle PV).
// Structural sweep R15-R21: occupancy/pipeline-depth/retile all null or
// negative; HBM-round-trip removal (R18) + barrier halving (R21) were the
// wins. This configuration is the measured local optimum.
// LDS map:
//   [0..24576)      staging buf0 -> K[192][64] swz after GEMM
//   [24576..49152)  staging buf1 -> Vt[64][192] swz after GEMM
//   [49152..73728)  staging buf2 -> Q[192][64] swz (x0.125) after GEMM
// ---------------------------------------------------------------------------
#define KO2   0
#define VTO2  24576
#define QO3   49152

__global__ __launch_bounds__(256, 2) void fused_qkv_attn(
    const bf16* __restrict__ hsb, const bf16* __restrict__ Wb2,
    const float* __restrict__ bq, const float* __restrict__ bk, const float* __restrict__ bv,
    const float* __restrict__ amask,
    const unsigned long long* __restrict__ bits,
    float* __restrict__ out)
{
    __shared__ char L[73728];
    const int tid  = threadIdx.x;
    const int lane = tid & 63;
    const int wid  = tid >> 6;
    const int wr = wid >> 1, wc = wid & 1;      // 2x2 wave grid, 96x96 each
    const int lm = lane & 15, lg = lane >> 4;

    // m204 XCD chunking (1536 = 8*192): 12 head-blocks of one b on one XCD.
    const int flat = blockIdx.x;
    const int wgid = (flat & 7) * 192 + (flat >> 3);
    const int b = wgid / NH, h = wgid - b * NH;

    float* obase = out + (size_t)b * NF * DMODEL + h * HDIM;

    // ---- aw: amask ballot words, per-wave registers (no LDS, no sync) ----
    unsigned long long aw0, aw1, aw2;
    {
        int k0 = lane, k1 = 64 + lane, k2 = 128 + lane;
        aw0 = __ballot(amask[b * NF + k0] == 0.0f);
        aw1 = __ballot(amask[b * NF + k1] == 0.0f);
        aw2 = __ballot((k2 < NF) && (amask[b * NF + k2] == 0.0f));
    }
    // decode output rows are exactly zero
    for (int i = tid; i < 12 * 64; i += 256)
        obase[(size_t)(170 + (i >> 6)) * DMODEL + (i & 63)] = 0.f;

    // ---- Phase G: GEMM (BK=32, 3-buffer ring, 1 barrier/iter, vmcnt(6)) ----
    const char* gA = (const char*)(hsb + (size_t)b * NF * DMODEL);   // 192 rows (pad rows in slack)
    const char* gW = (const char*)(Wb2 + (size_t)h * 192 * DMODEL);

    f32x4 acc[6][6];
    #pragma unroll
    for (int i = 0; i < 6; ++i)
        #pragma unroll
        for (int j = 0; j < 6; ++j) acc[i][j] = (f32x4){0.f, 0.f, 0.f, 0.f};

    const int srow4 = tid >> 2, sch4 = tid & 3;

    auto ST = [&](int kt, int bsel) {
        char* dA = L + bsel * 24576;
        char* dW = dA + 12288;
        #pragma unroll
        for (int it = 0; it < 3; ++it) {
            int row = it * 64 + srow4;
            int lc = sch4 ^ ((row >> 1) & 3);
            size_t go = (size_t)row * 1536 + (size_t)kt * 64 + lc * 16;
            int o = row * 64 + sch4 * 16;
            gload_lds16(gA + go, dA + o);
            gload_lds16(gW + go, dW + o);
        }
    };
    auto CP = [&](int bsel) {
        const char* Ab = L + bsel * 24576;
        const char* Wp = Ab + 12288;
        s16x8 af[6], bf6[6];
        #pragma unroll
        for (int mi = 0; mi < 6; ++mi) {
            int r = 96 * wr + 16 * mi + lm;
            af[mi] = *reinterpret_cast<const s16x8*>(Ab + r * 64 + ((lg ^ ((r >> 1) & 3)) << 4));
        }
        #pragma unroll
        for (int ni = 0; ni < 6; ++ni) {
            int r = 96 * wc + 16 * ni + lm;
            bf6[ni] = *reinterpret_cast<const s16x8*>(Wp + r * 64 + ((lg ^ ((r >> 1) & 3)) << 4));
        }
        __builtin_amdgcn_s_setprio(1);
        #pragma unroll
        for (int mi = 0; mi < 6; ++mi)
            #pragma unroll
            for (int ni = 0; ni < 6; ++ni)
                acc[mi][ni] = __builtin_amdgcn_mfma_f32_16x16x32_bf16(af[mi], bf6[ni], acc[mi][ni], 0, 0, 0);
        __builtin_amdgcn_s_setprio(0);
    };

    // prologue: two tiles in flight
    ST(0, 0);
    ST(1, 1);
    for (int t = 0; t < 24; ++t) {
        // wait tile t landed (tiles t, t+1 outstanding -> allow 6 loads in flight)
        if (t < 23) { asm volatile("s_waitcnt vmcnt(6)" ::: "memory"); }
        else        { asm volatile("s_waitcnt vmcnt(0)" ::: "memory"); }
        SB(); BAR(); SB();
        // ST into buf consumed at CP(t-1): all waves past it (they crossed BAR)
        if (t + 2 < 24) ST(t + 2, (t + 2) % 3);
        CP(t % 3);
        SB();
    }
    BAR();   // all CP reads done before epilogue overwrites staging region

    // ---- epilogue (SINGLE PASS): acc+bias -> Q/K/Vt LDS ----
    float bias6[6];
    #pragma unroll
    for (int ni = 0; ni < 6; ++ni) {
        int c = 96 * wc + 16 * ni + lm;
        int whichc = c >> 6, cc = c & 63;
        const float* bp = (whichc == 0) ? bq : (whichc == 1) ? bk : bv;
        bias6[ni] = bp[h * 64 + cc];
    }
    #pragma unroll
    for (int mi = 0; mi < 6; ++mi) {
        #pragma unroll
        for (int ni = 0; ni < 6; ++ni) {
            int c = 96 * wc + 16 * ni + lm;
            int row0 = 96 * wr + 16 * mi + 4 * lg;
            if (c < 64) {
                // Q, pre-scaled by 1/8 (exact pow2 in bf16)
                #pragma unroll
                for (int j = 0; j < 4; ++j) {
                    int row = row0 + j;
                    bf16 hv = __float2bfloat16((acc[mi][ni][j] + bias6[ni]) * 0.125f);
                    *reinterpret_cast<unsigned short*>(L + QO3 + row * 128 + ((2 * c) ^ ((row & 7) << 4))) =
                        *reinterpret_cast<unsigned short*>(&hv);
                }
            } else if (c < 128) {
                int cc = c - 64;
                #pragma unroll
                for (int j = 0; j < 4; ++j) {
                    int row = row0 + j;
                    bf16 hv = __float2bfloat16(acc[mi][ni][j] + bias6[ni]);
                    *reinterpret_cast<unsigned short*>(L + KO2 + row * 128 + ((2 * cc) ^ ((row & 7) << 4))) =
                        *reinterpret_cast<unsigned short*>(&hv);
                }
            } else {
                int d = c - 128;
                if (row0 + 3 < NF) {
                    union { unsigned long long u8; bf16 h[4]; } pk;
                    pk.h[0] = __float2bfloat16(acc[mi][ni][0] + bias6[ni]);
                    pk.h[1] = __float2bfloat16(acc[mi][ni][1] + bias6[ni]);
                    pk.h[2] = __float2bfloat16(acc[mi][ni][2] + bias6[ni]);
                    pk.h[3] = __float2bfloat16(acc[mi][ni][3] + bias6[ni]);
                    *reinterpret_cast<unsigned long long*>(L + VTO2 + d * 384 + ((2 * row0) ^ ((d & 7) << 4))) = pk.u8;
                } else {
                    #pragma unroll
                    for (int j = 0; j < 4; ++j) {
                        int row = row0 + j;
                        if (row < NF) {
                            bf16 hv = __float2bfloat16(acc[mi][ni][j] + bias6[ni]);
                            *reinterpret_cast<unsigned short*>(L + VTO2 + d * 384 + ((2 * row) ^ ((d & 7) << 4))) =
                                *reinterpret_cast<unsigned short*>(&hv);
                        }
                    }
                }
            }
        }
    }
    // zero Vt pad keys 182..191 (only writer of these addresses -> race-free)
    for (int i = tid; i < 64 * 10; i += 256) {
        int d = i / 10, k2 = NF + (i - d * 10);
        *reinterpret_cast<unsigned short*>(L + VTO2 + d * 384 + ((2 * k2) ^ ((d & 7) << 4))) = 0;
    }
    __syncthreads();

    // ---- Q-preload from LDS (verified addressing) ----
    s16x8 qf[3][2];
    #pragma unroll
    for (int bi = 0; bi < 3; ++bi) {
        int band = wid + 4 * bi;
        int qrow = ((band < 11) ? band * 16 : 0) + lm;      // safe dummy for band>=11
        const char* qb = L + QO3 + qrow * 128;
        int sq = (qrow & 7) << 4;
        qf[bi][0] = *reinterpret_cast<const s16x8*>(qb + ((lg * 16) ^ sq));
        qf[bi][1] = *reinterpret_cast<const s16x8*>(qb + ((64 + lg * 16) ^ sq));
    }

    // ---- Phase A: attention, P fully in-register (verified body) ----
    const unsigned long long* bbase = bits + ((size_t)b * NH + h) * ROCR * 3;
    const unsigned long long DEC = 0xFFFull << 42;          // keys 170..181

    #pragma unroll
    for (int bi = 0; bi < 3; ++bi) {
        const int band = wid + 4 * bi;
        if (band >= 11) continue;
        const int q0 = band * 16;

        // masks for this lane's q-row, straight from global bits (L2-hot)
        const int qrow = q0 + lm;
        unsigned long long mw0, mw1, mw2;
        if (qrow < SEQT) {
            mw0 = 0; mw1 = 0; mw2 = DEC & aw2;
        } else {
            const unsigned long long* bp = bbase + (size_t)(qrow - SEQT) * 3;
            mw0 = bp[0] & aw0;
            mw1 = bp[1] & aw1;
            mw2 = (bp[2] | DEC) & aw2;
        }

        // swapped QK^T: sacc[t][j] = S[key=16t+4lg+j][qrow=q0+lm] (pre-scaled)
        f32x4 sacc[12];
        #pragma unroll
        for (int t = 0; t < 12; ++t) sacc[t] = (f32x4){0.f, 0.f, 0.f, 0.f};
        #pragma unroll
        for (int t = 0; t < 12; ++t) {
            int key = t * 16 + lm;
            const char* kb = L + KO2 + key * 128;
            int sw = (key & 7) << 4;
            s16x8 kf0 = *reinterpret_cast<const s16x8*>(kb + ((lg * 16) ^ sw));
            s16x8 kf1 = *reinterpret_cast<const s16x8*>(kb + ((64 + lg * 16) ^ sw));
            sacc[t] = __builtin_amdgcn_mfma_f32_16x16x32_bf16(kf0, qf[bi][0], sacc[t], 0, 0, 0);
            sacc[t] = __builtin_amdgcn_mfma_f32_16x16x32_bf16(kf1, qf[bi][1], sacc[t], 0, 0, 0);
        }

        // mask + per-lane softmax (this lane owns one q-row)
        float mx = -3.0e38f;
        #pragma unroll
        for (int t = 0; t < 12; ++t) {
            unsigned long long w = (t < 4) ? mw0 : (t < 8) ? mw1 : mw2;
            #pragma unroll
            for (int j = 0; j < 4; ++j) {
                int sh = ((t & 3) << 4) + 4 * lg + j;
                float s = sacc[t][j];
                s = ((w >> sh) & 1ull) ? s : -3.0e38f;
                sacc[t][j] = s;
                mx = fmaxf(mx, s);
            }
        }
        mx = fmaxf(mx, __shfl_xor(mx, 16));
        mx = fmaxf(mx, __shfl_xor(mx, 32));
        float sum = 0.f;
        #pragma unroll
        for (int t = 0; t < 12; ++t)
            #pragma unroll
            for (int j = 0; j < 4; ++j) {
                float e = (sacc[t][j] > -1.0e37f) ? __expf(sacc[t][j] - mx) : 0.f;
                sacc[t][j] = e;
                sum += e;
            }
        sum += __shfl_xor(sum, 16);
        sum += __shfl_xor(sum, 32);
        float scl = (mx > -1.0e37f) ? 1.0f / sum : 0.f;

        // pack P rows to bf16 dword pairs per tile
        unsigned int p0[12], p1[12];
        #pragma unroll
        for (int t = 0; t < 12; ++t) {
            bf16 b0 = __float2bfloat16(sacc[t][0] * scl);
            bf16 b1 = __float2bfloat16(sacc[t][1] * scl);
            bf16 b2 = __float2bfloat16(sacc[t][2] * scl);
            bf16 b3 = __float2bfloat16(sacc[t][3] * scl);
            p0[t] = (unsigned int)*reinterpret_cast<unsigned short*>(&b0)
                  | ((unsigned int)*reinterpret_cast<unsigned short*>(&b1) << 16);
            p1[t] = (unsigned int)*reinterpret_cast<unsigned short*>(&b2)
                  | ((unsigned int)*reinterpret_cast<unsigned short*>(&b3) << 16);
        }

        // PV: build A-frags by lane exchange; dest (lg,ks) = keys 32ks+8lg+0..7
        f32x4 oacc[4];
        #pragma unroll
        for (int t = 0; t < 4; ++t) oacc[t] = (f32x4){0.f, 0.f, 0.f, 0.f};
        const bool hi = (lg & 1);
        #pragma unroll
        for (int ks = 0; ks < 6; ++ks) {
            unsigned int A0 = p0[2 * ks],     A1 = p1[2 * ks];
            unsigned int B0 = p0[2 * ks + 1], B1 = p1[2 * ks + 1];
            unsigned int u0 = __shfl_xor(A0, 16), u1 = __shfl_xor(A1, 16);
            unsigned int v0 = __shfl_xor(B0, 16), v1 = __shfl_xor(B1, 16);
            unsigned int hA0 = hi ? u0 : A0, hA1 = hi ? u1 : A1;
            unsigned int hA2 = hi ? A0 : u0, hA3 = hi ? A1 : u1;
            unsigned int hB0 = hi ? v0 : B0, hB1 = hi ? v1 : B1;
            unsigned int hB2 = hi ? B0 : v0, hB3 = hi ? B1 : v1;
            unsigned int xA0 = __shfl_xor(hA0, 32), xA1 = __shfl_xor(hA1, 32);
            unsigned int xA2 = __shfl_xor(hA2, 32), xA3 = __shfl_xor(hA3, 32);
            unsigned int xB0 = __shfl_xor(hB0, 32), xB1 = __shfl_xor(hB1, 32);
            unsigned int xB2 = __shfl_xor(hB2, 32), xB3 = __shfl_xor(hB3, 32);
            u32x4 f;
            if (lg == 0)      f = (u32x4){hA0, hA1, hA2, hA3};
            else if (lg == 1) f = (u32x4){xA0, xA1, xA2, xA3};
            else if (lg == 2) f = (u32x4){xB0, xB1, xB2, xB3};
            else              f = (u32x4){hB0, hB1, hB2, hB3};
            s16x8 pa;
            __builtin_memcpy(&pa, &f, 16);
            #pragma unroll
            for (int t2 = 0; t2 < 4; ++t2) {
                int d = t2 * 16 + lm;
                s16x8 vf = *reinterpret_cast<const s16x8*>(L + VTO2 + d * 384 + ((ks * 64 + lg * 16) ^ ((d & 7) << 4)));
                oacc[t2] = __builtin_amdgcn_mfma_f32_16x16x32_bf16(pa, vf, oacc[t2], 0, 0, 0);
            }
        }
        #pragma unroll
        for (int j = 0; j < 4; ++j) {
            int row = q0 + lg * 4 + j;
            if (row < 170) {
                #pragma unroll
                for (int t2 = 0; t2 < 4; ++t2)
                    obase[(size_t)row * DMODEL + t2 * 16 + lm] = oacc[t2][j];
            }
        }
    }
}

// ---------------------------------------------------------------------------
extern "C" void kernel_launch(void* const* d_in, const int* in_sizes, int n_in,
                              void* d_out, int out_size, void* d_ws, size_t ws_size,
                              hipStream_t stream)
{
    const float* hs    = (const float*)d_in[0];
    const float* amask = (const float*)d_in[1];
    const float* adj   = (const float*)d_in[2];
    const float* Wq    = (const float*)d_in[3];
    const float* bq    = (const float*)d_in[4];
    const float* Wk    = (const float*)d_in[5];
    const float* bk    = (const float*)d_in[6];
    const float* Wv    = (const float*)d_in[7];
    const float* bv    = (const float*)d_in[8];
    float* out = (float*)d_out;

    // workspace: Wb2 (3.54MB) | bits (5.53MB) | hsb (35.8MB + 16KB pad-row slack)
    char* ws = (char*)d_ws;
    bf16* Wb2 = (bf16*)ws;                                       // 2304*768*2 = 3,538,944
    unsigned long long* bits = (unsigned long long*)(ws + 3538944);
    bf16* hsb = (bf16*)(ws + 3538944 + 5529600);                 // 23296*768*2 = 35,782,656 (+slack)

    prep<<<dim3(CVT_BLOCKS + ROCR * NBS), 256, 0, stream>>>(hs, Wq, Wk, Wv, adj, hsb, Wb2, bits);
    fused_qkv_attn<<<dim3(NBS * NH), 256, 0, stream>>>(hsb, Wb2, bq, bk, bv, amask, bits, out);
}